// Round 1
// baseline (1506.392 us; speedup 1.0000x reference)
//
#include <hip/hip_runtime.h>

// Causal SDPA, B=4 H=16 S=2048 D=64, fp32 in/out.
// Outputs: context [B,H,S,64] then attn [B,H,S,S], flat-concatenated.
// Strategy: prepass converts K -> bf16 row-major and V -> bf16 transposed
// [bh][64][S] in workspace; main kernel: 1 WG (256 thr / 4 waves) per
// 16-query strip per (b,h); bf16 MFMA for QK^T and PV; score strip in LDS.

#define S 2048
#define DK 64
#define BH 64               // B*H
#define NSTRIP 128          // S/16
#define SCS 2056            // LDS score row stride (bf16 elems), 4112 B, 16B-aligned
#define VTS 2080            // V^T row stride (bf16 elems), 4160 B, breaks 4KB alias
#define CTX_ELEMS (BH * S * DK)   // 8388608

typedef __attribute__((ext_vector_type(8))) short bf16x8;
typedef __attribute__((ext_vector_type(4))) float f32x4;

__device__ __forceinline__ short f2bf(float f) {
    union { float f; unsigned u; } v; v.f = f;
    unsigned r = (v.u + 0x7FFFu + ((v.u >> 16) & 1u)) >> 16;
    return (short)r;
}
__device__ __forceinline__ float bf2f(short s) {
    union { unsigned u; float f; } v;
    v.u = ((unsigned)(unsigned short)s) << 16;
    return v.f;
}
__device__ __forceinline__ bf16x8 pack8(float4 x, float4 y) {
    bf16x8 r;
    r[0] = f2bf(x.x); r[1] = f2bf(x.y); r[2] = f2bf(x.z); r[3] = f2bf(x.w);
    r[4] = f2bf(y.x); r[5] = f2bf(y.y); r[6] = f2bf(y.z); r[7] = f2bf(y.w);
    return r;
}

// ---- prepass: K -> bf16 [bh][S][64]; V -> bf16 transposed [bh][64][VTS] ----
__global__ __launch_bounds__(256, 2)
void prepass_kernel(const float* __restrict__ K, const float* __restrict__ V,
                    short* __restrict__ Kbf, short* __restrict__ VT) {
    __shared__ short vt[64][72];     // 72: 144 B row stride, 16B-aligned, bank-spread
    const int bh = blockIdx.y;
    const int r0 = blockIdx.x * 64;  // 64-row chunk
    const int tid = threadIdx.x;

    // K convert: 64 rows x 64 cols in 8-elem units, coalesced
    for (int u = tid; u < 512; u += 256) {
        const int row = u >> 3, col = (u & 7) * 8;
        const size_t off = ((size_t)(bh * S + r0 + row)) * DK + col;
        float4 x = *(const float4*)(K + off);
        float4 y = *(const float4*)(K + off + 4);
        *(bf16x8*)(Kbf + off) = pack8(x, y);
    }
    // V chunk -> LDS transposed
    for (int u = tid; u < 512; u += 256) {
        const int row = u >> 3, col = (u & 7) * 8;
        const size_t off = ((size_t)(bh * S + r0 + row)) * DK + col;
        float4 x = *(const float4*)(V + off);
        float4 y = *(const float4*)(V + off + 4);
        bf16x8 p = pack8(x, y);
        #pragma unroll
        for (int j = 0; j < 8; ++j) vt[col + j][row] = p[j];
    }
    __syncthreads();
    // write V^T rows: thread -> (d = tid>>2, 16-col segment seg = tid&3)
    {
        const int d = tid >> 2, seg = tid & 3;
        bf16x8 a = *(const bf16x8*)&vt[d][seg * 16];
        bf16x8 b = *(const bf16x8*)&vt[d][seg * 16 + 8];
        short* dst = VT + ((size_t)(bh * DK + d)) * VTS + r0 + seg * 16;
        *(bf16x8*)dst = a;
        *(bf16x8*)(dst + 8) = b;
    }
}

template<bool PRE>
__global__ __launch_bounds__(256, 2)
void sdpa_causal_kernel(const float* __restrict__ Q,
                        const float* __restrict__ K,
                        const float* __restrict__ V,
                        const short* __restrict__ Kbf,
                        const short* __restrict__ VT,
                        float* __restrict__ out) {
    __shared__ short sc[16 * SCS];      // scores then e=exp(s-m), bf16
    __shared__ float row_inv[16];       // 1/l per strip row

    const int qb = NSTRIP - 1 - blockIdx.x;   // big strips dispatch first
    const int bh = blockIdx.y;
    const int qs = qb * 16;
    const int ncols = (qb + 1) * 16;          // valid key columns (tile-aligned)

    const int tid = threadIdx.x;
    const int w = tid >> 6;          // wave 0..3
    const int lane = tid & 63;
    const int quad = lane >> 4;      // 0..3
    const int mrow = lane & 15;      // A-frag m / C-frag col index

    float* ctx  = out;
    float* attn = out + (size_t)CTX_ELEMS;

    // ---- zero-fill score LDS (covers K=32 pad tile + safety) ----
    {
        int4 z = {0, 0, 0, 0};
        int4* p = (int4*)sc;
        const int nchunks = (16 * SCS * 2) / 16;   // 4112
        for (int i = tid; i < nchunks; i += 256) p[i] = z;
    }
    __syncthreads();

    // ---- Phase 1: S = scale * Q K^T  (causal masked), bf16 into LDS ----
    // A-frag: Q[qs+mrow][kc*32 + quad*8 + j]   (m=lane&15, k=quad*8+j)
    // B-frag: K[nt*16+mrow][kc*32 + quad*8 + j] (n=lane&15, k=quad*8+j)
    // C-frag: row = quad*4+reg, col = lane&15
    {
        bf16x8 aQ[2];
        const float* Qrow = Q + ((size_t)(bh * S + qs + mrow)) * DK;
        #pragma unroll
        for (int kc = 0; kc < 2; ++kc) {
            float4 x = *(const float4*)(Qrow + kc * 32 + quad * 8);
            float4 y = *(const float4*)(Qrow + kc * 32 + quad * 8 + 4);
            aQ[kc] = pack8(x, y);
        }
        for (int nt = w; nt <= qb; nt += 4) {
            f32x4 acc = {0.f, 0.f, 0.f, 0.f};
            if (PRE) {
                const short* Krow = Kbf + ((size_t)(bh * S + nt * 16 + mrow)) * DK;
                bf16x8 bK0 = *(const bf16x8*)(Krow + quad * 8);
                bf16x8 bK1 = *(const bf16x8*)(Krow + 32 + quad * 8);
                acc = __builtin_amdgcn_mfma_f32_16x16x32_bf16(aQ[0], bK0, acc, 0, 0, 0);
                acc = __builtin_amdgcn_mfma_f32_16x16x32_bf16(aQ[1], bK1, acc, 0, 0, 0);
            } else {
                const float* Krow = K + ((size_t)(bh * S + nt * 16 + mrow)) * DK;
                #pragma unroll
                for (int kc = 0; kc < 2; ++kc) {
                    float4 x = *(const float4*)(Krow + kc * 32 + quad * 8);
                    float4 y = *(const float4*)(Krow + kc * 32 + quad * 8 + 4);
                    bf16x8 bK = pack8(x, y);
                    acc = __builtin_amdgcn_mfma_f32_16x16x32_bf16(aQ[kc], bK, acc, 0, 0, 0);
                }
            }
            #pragma unroll
            for (int r = 0; r < 4; ++r) {
                int rloc = quad * 4 + r;           // strip row 0..15
                int gcol = nt * 16 + mrow;         // key column
                float val = acc[r] * 0.125f;
                if (gcol > qs + rloc) val = -INFINITY;   // causal mask
                sc[rloc * SCS + gcol] = f2bf(val);
            }
        }
    }
    __syncthreads();

    // ---- Phase 2: per-row softmax stats; overwrite s with e=exp(s-m) ----
    for (int r = 0; r < 4; ++r) {
        const int row = w * 4 + r;
        float mx = -INFINITY;
        for (int c = lane * 8; c < ncols; c += 512) {
            bf16x8 v = *(const bf16x8*)&sc[row * SCS + c];
            #pragma unroll
            for (int i = 0; i < 8; ++i) mx = fmaxf(mx, bf2f(v[i]));
        }
        #pragma unroll
        for (int off = 32; off; off >>= 1) mx = fmaxf(mx, __shfl_xor(mx, off));

        float sum = 0.f;
        for (int c = lane * 8; c < ncols; c += 512) {
            bf16x8 v = *(const bf16x8*)&sc[row * SCS + c];
            bf16x8 e;
            #pragma unroll
            for (int i = 0; i < 8; ++i) {
                float ev = __expf(bf2f(v[i]) - mx);
                sum += ev;
                e[i] = f2bf(ev);
            }
            *(bf16x8*)&sc[row * SCS + c] = e;
        }
        #pragma unroll
        for (int off = 32; off; off >>= 1) sum += __shfl_xor(sum, off);
        if (lane == 0) row_inv[row] = 1.0f / sum;
    }
    __syncthreads();

    // ---- Phase 3: write attn = e * (1/l)  + zeros for masked cols ----
    // One full row per iteration: 256 thr x 8 cols = 2048 = S.
    {
        float* attnBase = attn + (size_t)(bh * S + qs) * S;
        const int c = tid * 8;
        for (int row = 0; row < 16; ++row) {
            float* dst = attnBase + (size_t)row * S + c;
            if (c < ncols) {
                const float invl = row_inv[row];
                bf16x8 v = *(const bf16x8*)&sc[row * SCS + c];
                float4 o0, o1;
                o0.x = bf2f(v[0]) * invl; o0.y = bf2f(v[1]) * invl;
                o0.z = bf2f(v[2]) * invl; o0.w = bf2f(v[3]) * invl;
                o1.x = bf2f(v[4]) * invl; o1.y = bf2f(v[5]) * invl;
                o1.z = bf2f(v[6]) * invl; o1.w = bf2f(v[7]) * invl;
                *(float4*)dst = o0;
                *(float4*)(dst + 4) = o1;
            } else {
                float4 z = {0.f, 0.f, 0.f, 0.f};
                *(float4*)dst = z;
                *(float4*)(dst + 4) = z;
            }
        }
    }

    // ---- Phase 4: O = (e . V) * (1/l) via MFMA, j-chunks split over waves ----
    f32x4 o0 = {0.f,0.f,0.f,0.f}, o1 = o0, o2 = o0, o3 = o0;
    {
        const int NC32 = (ncols + 31) >> 5;
        if (PRE) {
            const short* VTb = VT + (size_t)bh * DK * VTS;
            for (int c = w; c < NC32; c += 4) {
                const int j0 = c * 32;
                // A-frag: e[mrow][j0 + quad*8 + j]  (contiguous 16B in LDS)
                bf16x8 aP = *(const bf16x8*)&sc[mrow * SCS + j0 + quad * 8];
                // B-frags: V^T[dt*16+mrow][j0 + quad*8 + jj] = 16B vector loads
                #pragma unroll
                for (int dt = 0; dt < 4; ++dt) {
                    bf16x8 bV = *(const bf16x8*)&VTb[(size_t)(dt * 16 + mrow) * VTS + j0 + quad * 8];
                    f32x4 acc = dt == 0 ? o0 : dt == 1 ? o1 : dt == 2 ? o2 : o3;
                    acc = __builtin_amdgcn_mfma_f32_16x16x32_bf16(aP, bV, acc, 0, 0, 0);
                    if      (dt == 0) o0 = acc;
                    else if (dt == 1) o1 = acc;
                    else if (dt == 2) o2 = acc;
                    else              o3 = acc;
                }
            }
        } else {
            for (int c = w; c < NC32; c += 4) {
                const int j0 = c * 32;
                bf16x8 aP = *(const bf16x8*)&sc[mrow * SCS + j0 + quad * 8];
                #pragma unroll
                for (int dt = 0; dt < 4; ++dt) {
                    const float* Vp = V + ((size_t)(bh * S + j0 + quad * 8)) * DK + dt * 16 + mrow;
                    bf16x8 bV;
                    #pragma unroll
                    for (int jj = 0; jj < 8; ++jj) bV[jj] = f2bf(Vp[jj * DK]);
                    f32x4 acc = dt == 0 ? o0 : dt == 1 ? o1 : dt == 2 ? o2 : o3;
                    acc = __builtin_amdgcn_mfma_f32_16x16x32_bf16(aP, bV, acc, 0, 0, 0);
                    if      (dt == 0) o0 = acc;
                    else if (dt == 1) o1 = acc;
                    else if (dt == 2) o2 = acc;
                    else              o3 = acc;
                }
            }
        }
    }
    __syncthreads();   // sc (e-values) dead after this point

    // ---- cross-wave O reduction through LDS (overlay on sc) ----
    {
        float* op = (float*)sc;   // [4 waves][16 rows][64 d] = 16 KB
        #pragma unroll
        for (int dt = 0; dt < 4; ++dt) {
            f32x4 acc = dt == 0 ? o0 : dt == 1 ? o1 : dt == 2 ? o2 : o3;
            #pragma unroll
            for (int r = 0; r < 4; ++r)
                op[(w * 16 + quad * 4 + r) * 64 + dt * 16 + mrow] = acc[r];
        }
        __syncthreads();
        #pragma unroll
        for (int k = 0; k < 4; ++k) {
            int idx = tid + k * 256;         // 0..1023
            int row = idx >> 6, d = idx & 63;
            float s = op[row * 64 + d] + op[(16 + row) * 64 + d]
                    + op[(32 + row) * 64 + d] + op[(48 + row) * 64 + d];
            ctx[((size_t)(bh * S + qs + row)) * DK + d] = s * row_inv[row];
        }
    }
}

extern "C" void kernel_launch(void* const* d_in, const int* in_sizes, int n_in,
                              void* d_out, int out_size, void* d_ws, size_t ws_size,
                              hipStream_t stream) {
    const float* Q = (const float*)d_in[0];
    const float* K = (const float*)d_in[1];
    const float* V = (const float*)d_in[2];
    // d_in[3] = attn_mask (causal, known statically) - unused
    float* out = (float*)d_out;
    dim3 grid(NSTRIP, BH);

    const size_t kbf_bytes = (size_t)BH * S * DK * sizeof(short);        // 16.78 MB
    const size_t vt_bytes  = (size_t)BH * DK * VTS * sizeof(short);      // 17.04 MB
    if (ws_size >= kbf_bytes + vt_bytes) {
        short* Kbf = (short*)d_ws;
        short* VT  = (short*)((char*)d_ws + kbf_bytes);
        prepass_kernel<<<dim3(S / 64, BH), 256, 0, stream>>>(K, V, Kbf, VT);
        sdpa_causal_kernel<true><<<grid, 256, 0, stream>>>(Q, K, V, Kbf, VT, out);
    } else {
        sdpa_causal_kernel<false><<<grid, 256, 0, stream>>>(Q, K, V, nullptr, nullptr, out);
    }
}

// Round 2
// 1452.365 us; speedup vs baseline: 1.0372x; 1.0372x over previous
//
#include <hip/hip_runtime.h>

// Causal SDPA, B=4 H=16 S=2048 D=64, fp32 in/out.
// Outputs: context [B,H,S,64] then attn [B,H,S,S], flat-concatenated.
// r2: swapped-operand QK^T (mfma(K,Q)) makes each lane own one q-row ->
// register-resident online softmax stats (pass 1), then recompute scores
// (pass 2) writing attn straight from registers + PV via tiny per-wave LDS.
// LDS 65.8KB -> 21.6KB (occupancy 2 -> 4+ blocks/CU), barriers 5 -> 2.

#define S 2048
#define DK 64
#define BH 64               // B*H
#define NSTRIP 128          // S/16
#define VTS 2080            // V^T row stride (bf16 elems), breaks 4KB alias
#define ELD 40              // e-chunk LDS row stride (shorts), 80B
#define CTX_ELEMS (BH * S * DK)   // 8388608

typedef __attribute__((ext_vector_type(8))) short bf16x8;
typedef __attribute__((ext_vector_type(4))) short bf16x4;
typedef __attribute__((ext_vector_type(4))) float f32x4;

__device__ __forceinline__ short f2bf(float f) {
    union { float f; unsigned u; } v; v.f = f;
    unsigned r = (v.u + 0x7FFFu + ((v.u >> 16) & 1u)) >> 16;
    return (short)r;
}
__device__ __forceinline__ float bf2f(short s) {
    union { unsigned u; float f; } v;
    v.u = ((unsigned)(unsigned short)s) << 16;
    return v.f;
}
__device__ __forceinline__ bf16x8 pack8(float4 x, float4 y) {
    bf16x8 r;
    r[0] = f2bf(x.x); r[1] = f2bf(x.y); r[2] = f2bf(x.z); r[3] = f2bf(x.w);
    r[4] = f2bf(y.x); r[5] = f2bf(y.y); r[6] = f2bf(y.z); r[7] = f2bf(y.w);
    return r;
}

// ---- prepass: K -> bf16 [bh][S][64]; V -> bf16 transposed [bh][64][VTS] ----
__global__ __launch_bounds__(256, 2)
void prepass_kernel(const float* __restrict__ K, const float* __restrict__ V,
                    short* __restrict__ Kbf, short* __restrict__ VT) {
    __shared__ short vt[64][72];
    const int bh = blockIdx.y;
    const int r0 = blockIdx.x * 64;
    const int tid = threadIdx.x;

    for (int u = tid; u < 512; u += 256) {
        const int row = u >> 3, col = (u & 7) * 8;
        const size_t off = ((size_t)(bh * S + r0 + row)) * DK + col;
        float4 x = *(const float4*)(K + off);
        float4 y = *(const float4*)(K + off + 4);
        *(bf16x8*)(Kbf + off) = pack8(x, y);
    }
    for (int u = tid; u < 512; u += 256) {
        const int row = u >> 3, col = (u & 7) * 8;
        const size_t off = ((size_t)(bh * S + r0 + row)) * DK + col;
        float4 x = *(const float4*)(V + off);
        float4 y = *(const float4*)(V + off + 4);
        bf16x8 p = pack8(x, y);
        #pragma unroll
        for (int j = 0; j < 8; ++j) vt[col + j][row] = p[j];
    }
    __syncthreads();
    {
        const int d = tid >> 2, seg = tid & 3;
        bf16x8 a = *(const bf16x8*)&vt[d][seg * 16];
        bf16x8 b = *(const bf16x8*)&vt[d][seg * 16 + 8];
        short* dst = VT + ((size_t)(bh * DK + d)) * VTS + r0 + seg * 16;
        *(bf16x8*)dst = a;
        *(bf16x8*)(dst + 8) = b;
    }
}

// ---- main kernel: swapped-operand two-pass ----
__global__ __launch_bounds__(256, 4)
void sdpa_causal_main(const float* __restrict__ Q,
                      const short* __restrict__ Kbf,
                      const short* __restrict__ VT,
                      float* __restrict__ out) {
    __shared__ short elds[4][16][ELD];    // per-wave e chunk (q-major), 5.1 KB
    __shared__ float stats_m[4][16];
    __shared__ float stats_l[4][16];
    __shared__ float row_inv[16];
    __shared__ float osum[4][16][64];     // cross-wave O reduce, 16 KB

    // bijective XCD swizzle: 8 consecutive bh per XCD (~4MB K/V = L2-fit)
    const int id = blockIdx.y * NSTRIP + blockIdx.x;
    const int sw = (id & 7) * (NSTRIP * BH / 8) + (id >> 3);
    const int bh = sw >> 7;
    const int qb = NSTRIP - 1 - (sw & 127);   // big strips first within bh
    const int qs = qb * 16;
    const int ncols = (qb + 1) * 16;

    const int tid = threadIdx.x;
    const int w = tid >> 6, lane = tid & 63;
    const int quad = lane >> 4, mrow = lane & 15;
    const int qrow = qs + mrow;               // this lane's q-row

    float* ctx  = out;
    float* attn = out + (size_t)CTX_ELEMS;

    // Q B-frags (persist across both passes). B[n=mrow][k=quad*8+j].
    bf16x8 bQ0, bQ1;
    {
        const float* Qrow = Q + ((size_t)(bh * S + qrow)) * DK;
        float4 x0 = *(const float4*)(Qrow + quad * 8);
        float4 y0 = *(const float4*)(Qrow + quad * 8 + 4);
        bQ0 = pack8(x0, y0);
        float4 x1 = *(const float4*)(Qrow + 32 + quad * 8);
        float4 y1 = *(const float4*)(Qrow + 32 + quad * 8 + 4);
        bQ1 = pack8(x1, y1);
    }

    // ---- Pass 1: online (m,l) per lane; C-frag: (key=nt*16+quad*4+r, q=mrow)
    float m0 = -1e30f, l0 = 0.f;
    for (int nt = w; nt <= qb; nt += 4) {
        const short* Krow = Kbf + ((size_t)(bh * S + nt * 16 + mrow)) * DK;
        bf16x8 aK0 = *(const bf16x8*)(Krow + quad * 8);
        bf16x8 aK1 = *(const bf16x8*)(Krow + 32 + quad * 8);
        f32x4 acc = {0.f, 0.f, 0.f, 0.f};
        acc = __builtin_amdgcn_mfma_f32_16x16x32_bf16(aK0, bQ0, acc, 0, 0, 0);
        acc = __builtin_amdgcn_mfma_f32_16x16x32_bf16(aK1, bQ1, acc, 0, 0, 0);
        const int keyb = nt * 16 + quad * 4;
        float s0 = (keyb + 0 <= qrow) ? acc[0] * 0.125f : -1e30f;
        float s1 = (keyb + 1 <= qrow) ? acc[1] * 0.125f : -1e30f;
        float s2 = (keyb + 2 <= qrow) ? acc[2] * 0.125f : -1e30f;
        float s3 = (keyb + 3 <= qrow) ? acc[3] * 0.125f : -1e30f;
        float t = fmaxf(fmaxf(s0, s1), fmaxf(s2, s3));
        float mn = fmaxf(m0, t);
        l0 = l0 * __expf(m0 - mn)
           + __expf(s0 - mn) + __expf(s1 - mn)
           + __expf(s2 - mn) + __expf(s3 - mn);
        m0 = mn;
    }
    // merge the 4 lanes (quads) sharing this q-row
    #pragma unroll
    for (int off = 16; off <= 32; off <<= 1) {
        float m2 = __shfl_xor(m0, off);
        float l2 = __shfl_xor(l0, off);
        float mg = fmaxf(m0, m2);
        l0 = l0 * __expf(m0 - mg) + l2 * __expf(m2 - mg);
        m0 = mg;
    }
    if (lane < 16) { stats_m[w][lane] = m0; stats_l[w][lane] = l0; }

    // attn tail zeros (cols >= ncols); stores drain under the barrier
    {
        float* base = attn + (size_t)(bh * S + qs) * S;
        const float4 z = {0.f, 0.f, 0.f, 0.f};
        for (int row = 0; row < 16; ++row)
            for (int c = ncols + tid * 4; c < S; c += 1024)
                *(float4*)(base + (size_t)row * S + c) = z;
    }
    __syncthreads();

    // final stats for this lane's q-row (redundant across lanes/waves)
    float mF = stats_m[0][mrow], lF = stats_l[0][mrow];
    #pragma unroll
    for (int ww = 1; ww < 4; ++ww) {
        float m2 = stats_m[ww][mrow], l2 = stats_l[ww][mrow];
        float mg = fmaxf(mF, m2);
        lF = lF * __expf(mF - mg) + l2 * __expf(m2 - mg);
        mF = mg;
    }
    const float invl = 1.f / lF;
    if (w == 0 && lane < 16) row_inv[lane] = invl;

    // ---- Pass 2: recompute scores; write attn from regs; PV via wave-LDS ----
    f32x4 o0 = {0.f,0.f,0.f,0.f}, o1 = o0, o2 = o0, o3 = o0;
    short* erow = &elds[w][mrow][0];
    const short* VTb = VT + (size_t)bh * DK * VTS;
    float* attnRow = attn + ((size_t)(bh * S + qrow)) * S;
    const int npair = (qb + 2) >> 1;
    for (int pp = w; pp < npair; pp += 4) {
        #pragma unroll
        for (int half = 0; half < 2; ++half) {
            const int nt = 2 * pp + half;
            if (nt <= qb) {
                const short* Krow = Kbf + ((size_t)(bh * S + nt * 16 + mrow)) * DK;
                bf16x8 aK0 = *(const bf16x8*)(Krow + quad * 8);
                bf16x8 aK1 = *(const bf16x8*)(Krow + 32 + quad * 8);
                f32x4 acc = {0.f, 0.f, 0.f, 0.f};
                acc = __builtin_amdgcn_mfma_f32_16x16x32_bf16(aK0, bQ0, acc, 0, 0, 0);
                acc = __builtin_amdgcn_mfma_f32_16x16x32_bf16(aK1, bQ1, acc, 0, 0, 0);
                const int keyb = nt * 16 + quad * 4;
                float e0, e1, e2, e3;
                {
                    float sv;
                    sv = (keyb + 0 <= qrow) ? acc[0] * 0.125f : -1e30f; e0 = __expf(sv - mF);
                    sv = (keyb + 1 <= qrow) ? acc[1] * 0.125f : -1e30f; e1 = __expf(sv - mF);
                    sv = (keyb + 2 <= qrow) ? acc[2] * 0.125f : -1e30f; e2 = __expf(sv - mF);
                    sv = (keyb + 3 <= qrow) ? acc[3] * 0.125f : -1e30f; e3 = __expf(sv - mF);
                }
                float4 av;
                av.x = e0 * invl; av.y = e1 * invl;
                av.z = e2 * invl; av.w = e3 * invl;
                *(float4*)(attnRow + keyb) = av;
                bf16x4 eb;
                eb[0] = f2bf(e0); eb[1] = f2bf(e1);
                eb[2] = f2bf(e2); eb[3] = f2bf(e3);
                *(bf16x4*)(erow + half * 16 + quad * 4) = eb;
            } else {
                bf16x4 zb = {0, 0, 0, 0};
                *(bf16x4*)(erow + half * 16 + quad * 4) = zb;
            }
        }
        // PV over this pair's 32 keys: A-frag e[q=mrow][k=quad*8+j]
        bf16x8 aP = *(const bf16x8*)&elds[w][mrow][quad * 8];
        const size_t vco = (size_t)pp * 32 + quad * 8;
        #pragma unroll
        for (int dt = 0; dt < 4; ++dt) {
            bf16x8 bV = *(const bf16x8*)(VTb + (size_t)(dt * 16 + mrow) * VTS + vco);
            f32x4 a = dt == 0 ? o0 : dt == 1 ? o1 : dt == 2 ? o2 : o3;
            a = __builtin_amdgcn_mfma_f32_16x16x32_bf16(aP, bV, a, 0, 0, 0);
            if      (dt == 0) o0 = a;
            else if (dt == 1) o1 = a;
            else if (dt == 2) o2 = a;
            else              o3 = a;
        }
    }

    // ---- cross-wave O reduction; C-frag O[q=quad*4+r][d=dt*16+mrow] ----
    #pragma unroll
    for (int dt = 0; dt < 4; ++dt) {
        f32x4 a = dt == 0 ? o0 : dt == 1 ? o1 : dt == 2 ? o2 : o3;
        #pragma unroll
        for (int r = 0; r < 4; ++r)
            osum[w][quad * 4 + r][dt * 16 + mrow] = a[r];
    }
    __syncthreads();
    #pragma unroll
    for (int k = 0; k < 4; ++k) {
        int idx = tid + k * 256;
        int row = idx >> 6, d = idx & 63;
        float sv = osum[0][row][d] + osum[1][row][d]
                 + osum[2][row][d] + osum[3][row][d];
        ctx[((size_t)(bh * S + qs + row)) * DK + d] = sv * row_inv[row];
    }
}

// ---- fallback (no workspace): fp32-direct single-pass (round-0 verified) ----
__global__ __launch_bounds__(256, 2)
void sdpa_causal_fb(const float* __restrict__ Q, const float* __restrict__ K,
                    const float* __restrict__ V, float* __restrict__ out) {
    __shared__ short sc[16 * 2056];
    __shared__ float row_inv[16];
    const int qb = NSTRIP - 1 - blockIdx.x;
    const int bh = blockIdx.y;
    const int qs = qb * 16;
    const int ncols = (qb + 1) * 16;
    const int tid = threadIdx.x;
    const int w = tid >> 6, lane = tid & 63;
    const int quad = lane >> 4, mrow = lane & 15;
    float* ctx  = out;
    float* attn = out + (size_t)CTX_ELEMS;
    {
        int4 z = {0,0,0,0};
        int4* p = (int4*)sc;
        for (int i = tid; i < (16 * 2056 * 2) / 16; i += 256) p[i] = z;
    }
    __syncthreads();
    {
        bf16x8 aQ[2];
        const float* Qrow = Q + ((size_t)(bh * S + qs + mrow)) * DK;
        #pragma unroll
        for (int kc = 0; kc < 2; ++kc) {
            float4 x = *(const float4*)(Qrow + kc * 32 + quad * 8);
            float4 y = *(const float4*)(Qrow + kc * 32 + quad * 8 + 4);
            aQ[kc] = pack8(x, y);
        }
        for (int nt = w; nt <= qb; nt += 4) {
            const float* Krow = K + ((size_t)(bh * S + nt * 16 + mrow)) * DK;
            f32x4 acc = {0.f,0.f,0.f,0.f};
            #pragma unroll
            for (int kc = 0; kc < 2; ++kc) {
                float4 x = *(const float4*)(Krow + kc * 32 + quad * 8);
                float4 y = *(const float4*)(Krow + kc * 32 + quad * 8 + 4);
                bf16x8 bK = pack8(x, y);
                acc = __builtin_amdgcn_mfma_f32_16x16x32_bf16(aQ[kc], bK, acc, 0, 0, 0);
            }
            #pragma unroll
            for (int r = 0; r < 4; ++r) {
                int rloc = quad * 4 + r;
                int gcol = nt * 16 + mrow;
                float val = acc[r] * 0.125f;
                if (gcol > qs + rloc) val = -INFINITY;
                sc[rloc * 2056 + gcol] = f2bf(val);
            }
        }
    }
    __syncthreads();
    for (int r = 0; r < 4; ++r) {
        const int row = w * 4 + r;
        float mx = -INFINITY;
        for (int c = lane * 8; c < ncols; c += 512) {
            bf16x8 v = *(const bf16x8*)&sc[row * 2056 + c];
            #pragma unroll
            for (int i = 0; i < 8; ++i) mx = fmaxf(mx, bf2f(v[i]));
        }
        #pragma unroll
        for (int off = 32; off; off >>= 1) mx = fmaxf(mx, __shfl_xor(mx, off));
        float sum = 0.f;
        for (int c = lane * 8; c < ncols; c += 512) {
            bf16x8 v = *(const bf16x8*)&sc[row * 2056 + c];
            bf16x8 e;
            #pragma unroll
            for (int i = 0; i < 8; ++i) {
                float ev = __expf(bf2f(v[i]) - mx);
                sum += ev; e[i] = f2bf(ev);
            }
            *(bf16x8*)&sc[row * 2056 + c] = e;
        }
        #pragma unroll
        for (int off = 32; off; off >>= 1) sum += __shfl_xor(sum, off);
        if (lane == 0) row_inv[row] = 1.0f / sum;
    }
    __syncthreads();
    {
        float* attnBase = attn + (size_t)(bh * S + qs) * S;
        const int c = tid * 8;
        for (int row = 0; row < 16; ++row) {
            float* dst = attnBase + (size_t)row * S + c;
            if (c < ncols) {
                const float invl = row_inv[row];
                bf16x8 v = *(const bf16x8*)&sc[row * 2056 + c];
                float4 a0, a1;
                a0.x = bf2f(v[0]) * invl; a0.y = bf2f(v[1]) * invl;
                a0.z = bf2f(v[2]) * invl; a0.w = bf2f(v[3]) * invl;
                a1.x = bf2f(v[4]) * invl; a1.y = bf2f(v[5]) * invl;
                a1.z = bf2f(v[6]) * invl; a1.w = bf2f(v[7]) * invl;
                *(float4*)dst = a0; *(float4*)(dst + 4) = a1;
            } else {
                float4 z = {0.f,0.f,0.f,0.f};
                *(float4*)dst = z; *(float4*)(dst + 4) = z;
            }
        }
    }
    f32x4 o0 = {0.f,0.f,0.f,0.f}, o1 = o0, o2 = o0, o3 = o0;
    {
        const int NC32 = (ncols + 31) >> 5;
        for (int c = w; c < NC32; c += 4) {
            const int j0 = c * 32;
            bf16x8 aP = *(const bf16x8*)&sc[mrow * 2056 + j0 + quad * 8];
            #pragma unroll
            for (int dt = 0; dt < 4; ++dt) {
                const float* Vp = V + ((size_t)(bh * S + j0 + quad * 8)) * DK + dt * 16 + mrow;
                bf16x8 bV;
                #pragma unroll
                for (int jj = 0; jj < 8; ++jj) bV[jj] = f2bf(Vp[jj * DK]);
                f32x4 a = dt == 0 ? o0 : dt == 1 ? o1 : dt == 2 ? o2 : o3;
                a = __builtin_amdgcn_mfma_f32_16x16x32_bf16(aP, bV, a, 0, 0, 0);
                if      (dt == 0) o0 = a;
                else if (dt == 1) o1 = a;
                else if (dt == 2) o2 = a;
                else              o3 = a;
            }
        }
    }
    __syncthreads();
    {
        float* op = (float*)sc;
        #pragma unroll
        for (int dt = 0; dt < 4; ++dt) {
            f32x4 a = dt == 0 ? o0 : dt == 1 ? o1 : dt == 2 ? o2 : o3;
            #pragma unroll
            for (int r = 0; r < 4; ++r)
                op[(w * 16 + quad * 4 + r) * 64 + dt * 16 + mrow] = a[r];
        }
        __syncthreads();
        #pragma unroll
        for (int k = 0; k < 4; ++k) {
            int idx = tid + k * 256;
            int row = idx >> 6, d = idx & 63;
            float s = op[row * 64 + d] + op[(16 + row) * 64 + d]
                    + op[(32 + row) * 64 + d] + op[(48 + row) * 64 + d];
            ctx[((size_t)(bh * S + qs + row)) * DK + d] = s * row_inv[row];
        }
    }
}

extern "C" void kernel_launch(void* const* d_in, const int* in_sizes, int n_in,
                              void* d_out, int out_size, void* d_ws, size_t ws_size,
                              hipStream_t stream) {
    const float* Q = (const float*)d_in[0];
    const float* K = (const float*)d_in[1];
    const float* V = (const float*)d_in[2];
    float* out = (float*)d_out;
    dim3 grid(NSTRIP, BH);

    const size_t kbf_bytes = (size_t)BH * S * DK * sizeof(short);
    const size_t vt_bytes  = (size_t)BH * DK * VTS * sizeof(short);
    if (ws_size >= kbf_bytes + vt_bytes) {
        short* Kbf = (short*)d_ws;
        short* VT  = (short*)((char*)d_ws + kbf_bytes);
        prepass_kernel<<<dim3(S / 64, BH), 256, 0, stream>>>(K, V, Kbf, VT);
        sdpa_causal_main<<<grid, 256, 0, stream>>>(Q, Kbf, VT, out);
    } else {
        sdpa_causal_fb<<<grid, 256, 0, stream>>>(Q, K, V, out);
    }
}